// Round 2
// baseline (709.504 us; speedup 1.0000x reference)
//
#include <hip/hip_runtime.h>

// File-scope: forbid mul+add contraction so every fp32 mul and add rounds
// separately, matching numpy (which materializes z*z before pairwise-summing).
// Explicit fma() calls below still emit v_fma_f64.
#pragma clang fp contract(off)

#define K_CODES 512
#define D_DIM 256
// B*H*W = 64*32*32 = 65536 pixels; z_e_x layout [B, D, H, W]

__device__ double g_cbT[D_DIM * K_CODES];  // fp64 codebook, [d][k]
__device__ float  g_esq[K_CODES];          // numpy-pairwise fp32 ||e_k||^2

__global__ __launch_bounds__(256) void prep_kernel(const float* __restrict__ cb) {
    int k = blockIdx.x * 256 + threadIdx.x;
    if (k >= K_CODES) return;
    const float* row = cb + k * D_DIM;
    for (int d = 0; d < D_DIM; ++d)
        g_cbT[d * K_CODES + k] = (double)row[d];   // coalesced writes (k fastest)

    // e_sq = np.sum(row*row): pairwise, n=256 -> pair(0:128) + pair(128:256).
    // Each 128-block: r[j] = a[j]; r[j] += a[8t+j]; fold ((r0+r1)+(r2+r3))+((r4+r5)+(r6+r7)).
    float s[2];
    for (int blk = 0; blk < 2; ++blk) {
        const float* a = row + blk * 128;
        float r[8];
        #pragma unroll
        for (int j = 0; j < 8; ++j) { float x = a[j]; r[j] = x * x; }
        for (int i = 8; i < 128; i += 8)
            #pragma unroll
            for (int j = 0; j < 8; ++j) { float x = a[i + j]; r[j] += x * x; }
        s[blk] = ((r[0] + r[1]) + (r[2] + r[3])) + ((r[4] + r[5]) + (r[6] + r[7]));
    }
    g_esq[k] = s[0] + s[1];
}

// Block = 64 pixels x 512 codes; wave w owns codes [w*64, w*64+64).
__global__ __launch_bounds__(512, 2) void vq_argmin_kernel(
        const float* __restrict__ z, int* __restrict__ out) {
    const int lane = threadIdx.x & 63;
    const int w  = __builtin_amdgcn_readfirstlane((int)(threadIdx.x >> 6));
    const int ks = w * 64;

    const int n0 = blockIdx.x * 64;
    const int n  = n0 + lane;
    const int b  = n >> 10;                  // H*W = 1024
    const int hw = n & 1023;
    const float* zp = z + ((size_t)b << 18) + hw;

    double acc[64];
    #pragma unroll
    for (int k = 0; k < 64; ++k) acc[k] = 0.0;

    float r[8];          // numpy pairwise accumulators for z_sq
    float s_lo = 0.0f;

    for (int c = 0; c < D_DIM; c += 32) {
        float zf[32];
        #pragma unroll
        for (int i = 0; i < 32; ++i)
            zf[i] = zp[(size_t)(c + i) << 10];   // stride H*W, coalesced per lane

        // --- z_sq: exact numpy pairwise emulation (d ascending, r[d%8]) ---
        if (c == 0 || c == 128) {
            #pragma unroll
            for (int j = 0; j < 8; ++j) { float x = zf[j]; r[j] = x * x; }
            #pragma unroll
            for (int i = 8; i < 32; ++i) { float x = zf[i]; r[i & 7] += x * x; }
        } else {
            #pragma unroll
            for (int i = 0; i < 32; ++i) { float x = zf[i]; r[i & 7] += x * x; }
        }
        if (c == 96)  // block 0 (d 0..127) complete -> fold
            s_lo = ((r[0] + r[1]) + (r[2] + r[3])) + ((r[4] + r[5]) + (r[6] + r[7]));

        // --- cross in fp64 (error ~0 vs numpy's ~1.6e-8: below tie resolution) ---
        #pragma unroll 2
        for (int i = 0; i < 32; ++i) {
            double zd = (double)zf[i];
            const double* cr = &g_cbT[(c + i) * K_CODES + ks];  // wave-uniform -> s_load
            #pragma unroll
            for (int k = 0; k < 64; ++k)
                acc[k] = fma(cr[k], zd, acc[k]);
        }
    }
    float s_hi = ((r[0] + r[1]) + (r[2] + r[3])) + ((r[4] + r[5]) + (r[6] + r[7]));
    float zsq = s_lo + s_hi;   // pairwise(0:256) = p(0:128) + p(128:256)

    // numpy op order: t = fl32(zsq - fl32(2*c32)); dist = fl32(t + e_sq[k]).
    // Ascending k + strict '<' == numpy argmin first-index tie-break.
    float best = __builtin_inff(); int bi = ks;
    #pragma unroll
    for (int k = 0; k < 64; ++k) {
        float c32 = (float)acc[k];          // fl32(exact cross)
        float t = zsq - 2.0f * c32;         // 2*c32 exact; subtract rounds
        float dist = t + g_esq[ks + k];
        if (dist < best) { best = dist; bi = ks + k; }
    }

    __shared__ float s_best[8][64];
    __shared__ int   s_idx[8][64];
    s_best[w][lane] = best;
    s_idx[w][lane]  = bi;
    __syncthreads();

    if (threadIdx.x < 64) {   // lane == threadIdx.x
        float b0 = s_best[0][lane]; int i0 = s_idx[0][lane];
        #pragma unroll
        for (int q = 1; q < 8; ++q) {
            float bq = s_best[q][lane]; int iq = s_idx[q][lane];
            if (bq < b0 || (bq == b0 && iq < i0)) { b0 = bq; i0 = iq; }
        }
        out[n] = i0;
    }
}

extern "C" void kernel_launch(void* const* d_in, const int* in_sizes, int n_in,
                              void* d_out, int out_size, void* d_ws, size_t ws_size,
                              hipStream_t stream) {
    const float* z_e_x    = (const float*)d_in[0];   // [64, 256, 32, 32] fp32
    const float* codebook = (const float*)d_in[1];   // [512, 256] fp32
    int* out = (int*)d_out;                          // [65536] int32

    prep_kernel<<<dim3(2), dim3(256), 0, stream>>>(codebook);
    vq_argmin_kernel<<<dim3(1024), dim3(512), 0, stream>>>(z_e_x, out);
}

// Round 4
// 538.381 us; speedup vs baseline: 1.3178x; 1.3178x over previous
//
#include <hip/hip_runtime.h>

// contract(off): numpy-emulating fp32 ops (esq, zsq, final dist) must round
// mul and add separately. Hot loops use explicit fmaf/fma (still fused).
#pragma clang fp contract(off)

#define K_CODES 512
#define D_DIM 256
#define TAU 3e-4f
// B*H*W = 65536 pixels; z layout [B, D, H, W]; H*W = 1024.

__device__ float4 g_cbF4[(D_DIM / 4) * K_CODES]; // fp32 [d/4][k][4] (exact inputs)
__device__ float  g_esq[K_CODES];                // numpy-pairwise fp32 ||e_k||^2
__device__ int    g_list[65536];
__device__ int    g_count;

__global__ __launch_bounds__(256) void prep_kernel(const float* __restrict__ cb) {
    if (blockIdx.x == 0 && threadIdx.x == 0) g_count = 0;
    int k = blockIdx.x * 256 + threadIdx.x;
    if (k >= K_CODES) return;
    const float* row = cb + k * D_DIM;
    for (int dq = 0; dq < D_DIM / 4; ++dq)
        g_cbF4[dq * K_CODES + k] = make_float4(row[4*dq], row[4*dq+1], row[4*dq+2], row[4*dq+3]);

    // e_sq = np.sum(row*row): pairwise n=256 -> p(0:128)+p(128:256); 8 accums each.
    float s[2];
    for (int blk = 0; blk < 2; ++blk) {
        const float* a = row + blk * 128;
        float r[8];
        #pragma unroll
        for (int j = 0; j < 8; ++j) { float x = a[j]; r[j] = x * x; }
        for (int i = 8; i < 128; i += 8)
            #pragma unroll
            for (int j = 0; j < 8; ++j) { float x = a[i + j]; r[j] += x * x; }
        s[blk] = ((r[0] + r[1]) + (r[2] + r[3])) + ((r[4] + r[5]) + (r[6] + r[7]));
    }
    g_esq[k] = s[0] + s[1];
}

// Pass 1: block = 8 waves; wave w owns codes [w*64, w*64+64), lane = code.
// Block handles 32 pixels; z scalars are block-uniform (s_load through K$).
__global__ __launch_bounds__(512) void pass1_kernel(const float* __restrict__ z,
                                                    int* __restrict__ out) {
    const int lane = threadIdx.x & 63;
    const int w  = __builtin_amdgcn_readfirstlane((int)(threadIdx.x >> 6));
    const int k  = w * 64 + lane;
    const int ks = w * 64;

    const int n0  = __builtin_amdgcn_readfirstlane((int)blockIdx.x * 32);
    const float* zrow = z + ((size_t)(n0 >> 10) << 18) + (n0 & 1023);

    float acc[32];
    #pragma unroll
    for (int p = 0; p < 32; ++p) acc[p] = 0.0f;

    for (int d = 0; d < D_DIM; d += 4) {
        float4 c4 = g_cbF4[(d >> 2) * K_CODES + k];    // coalesced, per-lane
        float c[4] = {c4.x, c4.y, c4.z, c4.w};
        #pragma unroll
        for (int r = 0; r < 4; ++r) {
            const float4* z4 = (const float4*)(zrow + (size_t)(d + r) * 1024); // uniform
            #pragma unroll
            for (int pq = 0; pq < 8; ++pq) {
                float4 zq = z4[pq];
                acc[pq*4+0] = fmaf(c[r], zq.x, acc[pq*4+0]);
                acc[pq*4+1] = fmaf(c[r], zq.y, acc[pq*4+1]);
                acc[pq*4+2] = fmaf(c[r], zq.z, acc[pq*4+2]);
                acc[pq*4+3] = fmaf(c[r], zq.w, acc[pq*4+3]);
            }
        }
    }

    __shared__ float s_m1[8][32];
    __shared__ int   s_ix[8][32];
    __shared__ float s_gm[32];
    __shared__ int   s_cnt[8][32];

    const float esqk = g_esq[k];
    // Stage 1: per-wave min + first-min index.
    #pragma unroll
    for (int p = 0; p < 32; ++p) {
        float s = fmaf(-2.0f, acc[p], esqk);   // s[k] = e_sq - 2*cross
        acc[p] = s;                            // keep for stage 3
        float m = s;
        #pragma unroll
        for (int off = 32; off; off >>= 1) m = fminf(m, __shfl_xor(m, off));
        unsigned long long eq = __ballot(s == m);
        if (lane == 0) { s_m1[w][p] = m; s_ix[w][p] = ks + (__ffsll(eq) - 1); }
    }
    __syncthreads();

    // Stage 2: global min per pixel (strict < keeps lowest code range on ties;
    // exact cross-wave ties always get flagged in stage 3 and rescued).
    if (threadIdx.x < 32) {
        const int p = threadIdx.x;
        float m = s_m1[0][p]; int ix = s_ix[0][p];
        #pragma unroll
        for (int q = 1; q < 8; ++q)
            if (s_m1[q][p] < m) { m = s_m1[q][p]; ix = s_ix[q][p]; }
        s_gm[p] = m;
        s_ix[0][p] = ix;        // stash winner
    }
    __syncthreads();

    // Stage 3: count codes within TAU of the GLOBAL min (winner included).
    #pragma unroll
    for (int p = 0; p < 32; ++p) {
        float gm = s_gm[p];
        unsigned long long nr = __ballot(acc[p] < gm + TAU);
        if (lane == 0) s_cnt[w][p] = __popcll(nr);
    }
    __syncthreads();

    if (threadIdx.x < 32) {
        const int p = threadIdx.x;
        int cnt = 0;
        #pragma unroll
        for (int q = 0; q < 8; ++q) cnt += s_cnt[q][p];
        out[n0 + p] = s_ix[0][p];
        if (cnt >= 2) {                       // >=2 codes within TAU -> rescue
            int pos = atomicAdd(&g_count, 1);
            g_list[pos] = n0 + p;
        }
    }
}

// Rescue: numpy-bit-exact (round-2-validated formula). One wave per pixel.
// NO LDS: zsq computed redundantly per lane from wave-uniform loads.
__global__ __launch_bounds__(256) void rescue_kernel(const float* __restrict__ z,
                                                     int* __restrict__ out) {
    const int lane = threadIdx.x & 63;
    const int wg   = (int)blockIdx.x * 4 + (int)(threadIdx.x >> 6);
    const int nw   = (int)gridDim.x * 4;
    const int count = g_count;

    for (int it = wg; it < count; it += nw) {
        const int n = g_list[it];
        const float* zp = z + ((size_t)(n >> 10) << 18) + (n & 1023);

        // zsq: exact numpy pairwise (n=256 -> two 128-blocks, 8 accums, fold).
        float zsq;
        {
            float sb[2];
            #pragma unroll
            for (int blk = 0; blk < 2; ++blk) {
                const float* a = zp + ((size_t)blk << 17);   // +128*1024 floats
                float r[8];
                #pragma unroll
                for (int j = 0; j < 8; ++j) { float x = a[(size_t)j << 10]; r[j] = x * x; }
                for (int i = 8; i < 128; i += 8)
                    #pragma unroll
                    for (int j = 0; j < 8; ++j) { float x = a[(size_t)(i + j) << 10]; r[j] += x * x; }
                sb[blk] = ((r[0] + r[1]) + (r[2] + r[3])) + ((r[4] + r[5]) + (r[6] + r[7]));
            }
            zsq = sb[0] + sb[1];
        }

        // Exact cross in fp64 (fp32 cb widened: exact). lane handles k = lane+64j.
        double acc8[8];
        #pragma unroll
        for (int j = 0; j < 8; ++j) acc8[j] = 0.0;
        for (int dq = 0; dq < D_DIM / 4; ++dq) {
            double zd0 = (double)zp[(size_t)(4*dq + 0) << 10];   // uniform
            double zd1 = (double)zp[(size_t)(4*dq + 1) << 10];
            double zd2 = (double)zp[(size_t)(4*dq + 2) << 10];
            double zd3 = (double)zp[(size_t)(4*dq + 3) << 10];
            #pragma unroll
            for (int j = 0; j < 8; ++j) {
                float4 c4 = g_cbF4[dq * K_CODES + lane + (j << 6)];  // coalesced
                acc8[j] = fma((double)c4.x, zd0, acc8[j]);
                acc8[j] = fma((double)c4.y, zd1, acc8[j]);
                acc8[j] = fma((double)c4.z, zd2, acc8[j]);
                acc8[j] = fma((double)c4.w, zd3, acc8[j]);
            }
        }

        // numpy final ops: t = fl32(zsq - 2*c32); dist = fl32(t + esq). First-idx ties.
        float best = __builtin_inff(); int bi = 0x7FFFFFFF;
        #pragma unroll
        for (int j = 0; j < 8; ++j) {
            int kk = lane + (j << 6);
            float c32 = (float)acc8[j];
            float t = zsq - 2.0f * c32;
            float dist = t + g_esq[kk];
            if (dist < best || (dist == best && kk < bi)) { best = dist; bi = kk; }
        }
        #pragma unroll
        for (int off = 32; off; off >>= 1) {
            float ob = __shfl_xor(best, off);
            int   oi = __shfl_xor(bi, off);
            if (ob < best || (ob == best && oi < bi)) { best = ob; bi = oi; }
        }
        if (lane == 0) out[n] = bi;
    }
}

extern "C" void kernel_launch(void* const* d_in, const int* in_sizes, int n_in,
                              void* d_out, int out_size, void* d_ws, size_t ws_size,
                              hipStream_t stream) {
    const float* z_e_x    = (const float*)d_in[0];   // [64, 256, 32, 32] fp32
    const float* codebook = (const float*)d_in[1];   // [512, 256] fp32
    int* out = (int*)d_out;                          // [65536] int32

    prep_kernel<<<dim3(2), dim3(256), 0, stream>>>(codebook);
    pass1_kernel<<<dim3(2048), dim3(512), 0, stream>>>(z_e_x, out);
    rescue_kernel<<<dim3(128), dim3(256), 0, stream>>>(z_e_x, out);
}

// Round 5
// 425.233 us; speedup vs baseline: 1.6685x; 1.2661x over previous
//
#include <hip/hip_runtime.h>

// contract(off): numpy-emulating fp32 ops (esq, zsq, final dist) must round
// mul and add separately. Hot loops use explicit fmaf/fma (still fused).
#pragma clang fp contract(off)

#define K_CODES 512
#define D_DIM 256
#define TAU 3e-4f
// B*H*W = 65536 pixels; z layout [B, D, H, W]; H*W = 1024.

__device__ float4 g_cbF4[(D_DIM / 4) * K_CODES]; // fp32 [d/4][k][4] (exact inputs)
__device__ float  g_esq[K_CODES];                // numpy-pairwise fp32 ||e_k||^2
__device__ int    g_list[65536];
__device__ int    g_count;

__global__ __launch_bounds__(256) void prep_kernel(const float* __restrict__ cb) {
    if (blockIdx.x == 0 && threadIdx.x == 0) g_count = 0;
    int k = blockIdx.x * 256 + threadIdx.x;
    if (k >= K_CODES) return;
    const float* row = cb + k * D_DIM;
    for (int dq = 0; dq < D_DIM / 4; ++dq)
        g_cbF4[dq * K_CODES + k] = make_float4(row[4*dq], row[4*dq+1], row[4*dq+2], row[4*dq+3]);

    // e_sq = np.sum(row*row): pairwise n=256 -> p(0:128)+p(128:256); 8 accums each.
    float s[2];
    for (int blk = 0; blk < 2; ++blk) {
        const float* a = row + blk * 128;
        float r[8];
        #pragma unroll
        for (int j = 0; j < 8; ++j) { float x = a[j]; r[j] = x * x; }
        for (int i = 8; i < 128; i += 8)
            #pragma unroll
            for (int j = 0; j < 8; ++j) { float x = a[i + j]; r[j] += x * x; }
        s[blk] = ((r[0] + r[1]) + (r[2] + r[3])) + ((r[4] + r[5]) + (r[6] + r[7]));
    }
    g_esq[k] = s[0] + s[1];
}

// Pass 1: block = 8 waves; wave w owns codes [w*64, w*64+64), lane = code.
// Block handles 32 pixels. z loads forced to per-lane VMEM (broadcast) via an
// opaque LDS zero, double-buffered one row ahead in VGPRs (vmcnt pipelining;
// the SGPR/s_load path couldn't double-buffer: 2 rows = 64 SGPRs over budget).
__global__ __launch_bounds__(512) void pass1_kernel(const float* __restrict__ z,
                                                    int* __restrict__ out) {
    __shared__ int s_opq;
    __shared__ float s_m1[8][32];
    __shared__ int   s_ix[8][32];
    __shared__ float s_gm[32];
    __shared__ int   s_cnt[8][32];

    if (threadIdx.x == 0) s_opq = 0;
    __syncthreads();
    const int opq = s_opq;   // compiler can't prove uniform -> VMEM z loads

    const int lane = threadIdx.x & 63;
    const int w  = __builtin_amdgcn_readfirstlane((int)(threadIdx.x >> 6));
    const int k  = w * 64 + lane;
    const int ks = w * 64;

    const int n0 = __builtin_amdgcn_readfirstlane((int)blockIdx.x * 32);
    const float4* zr = (const float4*)(z + ((size_t)(n0 >> 10) << 18) + (n0 & 1023)) + opq;
    // quad q of row d lives at zr[d*256 + q]

    float acc[32];
    #pragma unroll
    for (int p = 0; p < 32; ++p) acc[p] = 0.0f;

    float4 A[8], Bf[8];
    #pragma unroll
    for (int q = 0; q < 8; ++q) A[q] = zr[q];        // row 0
    float4 c4cur = g_cbF4[k];                         // group 0

    for (int dg = 0; dg < 64; ++dg) {
        float4 c4nxt = g_cbF4[(dg < 63 ? dg + 1 : 63) * K_CODES + k];  // prefetch
        const int dbase = dg * 4;
        #pragma unroll
        for (int r = 0; r < 4; ++r) {
            const int dn = (dbase + r + 1 < 256) ? dbase + r + 1 : 255;
            #pragma unroll
            for (int q = 0; q < 8; ++q) Bf[q] = zr[dn * 256 + q];   // next row in flight
            const float cc = (r == 0) ? c4cur.x : (r == 1) ? c4cur.y
                           : (r == 2) ? c4cur.z : c4cur.w;
            #pragma unroll
            for (int q = 0; q < 8; ++q) {
                acc[q*4+0] = fmaf(cc, A[q].x, acc[q*4+0]);
                acc[q*4+1] = fmaf(cc, A[q].y, acc[q*4+1]);
                acc[q*4+2] = fmaf(cc, A[q].z, acc[q*4+2]);
                acc[q*4+3] = fmaf(cc, A[q].w, acc[q*4+3]);
            }
            #pragma unroll
            for (int q = 0; q < 8; ++q) A[q] = Bf[q];               // rotate
        }
        c4cur = c4nxt;
    }

    const float esqk = g_esq[k];
    // Stage 1: per-wave min + first-min index (identical to validated r4).
    #pragma unroll
    for (int p = 0; p < 32; ++p) {
        float s = fmaf(-2.0f, acc[p], esqk);   // s[k] = e_sq - 2*cross
        acc[p] = s;
        float m = s;
        #pragma unroll
        for (int off = 32; off; off >>= 1) m = fminf(m, __shfl_xor(m, off));
        unsigned long long eq = __ballot(s == m);
        if (lane == 0) { s_m1[w][p] = m; s_ix[w][p] = ks + (__ffsll(eq) - 1); }
    }
    __syncthreads();

    // Stage 2: global min per pixel.
    if (threadIdx.x < 32) {
        const int p = threadIdx.x;
        float m = s_m1[0][p]; int ix = s_ix[0][p];
        #pragma unroll
        for (int q = 1; q < 8; ++q)
            if (s_m1[q][p] < m) { m = s_m1[q][p]; ix = s_ix[q][p]; }
        s_gm[p] = m;
        s_ix[0][p] = ix;
    }
    __syncthreads();

    // Stage 3: count codes within TAU of the GLOBAL min (winner included).
    #pragma unroll
    for (int p = 0; p < 32; ++p) {
        float gm = s_gm[p];
        unsigned long long nr = __ballot(acc[p] < gm + TAU);
        if (lane == 0) s_cnt[w][p] = __popcll(nr);
    }
    __syncthreads();

    if (threadIdx.x < 32) {
        const int p = threadIdx.x;
        int cnt = 0;
        #pragma unroll
        for (int q = 0; q < 8; ++q) cnt += s_cnt[q][p];
        out[n0 + p] = s_ix[0][p];
        if (cnt >= 2) {
            int pos = atomicAdd(&g_count, 1);
            g_list[pos] = n0 + p;
        }
    }
}

// Rescue: numpy-bit-exact. One wave per pixel. z gathered per-lane (4 vector
// loads, all lines in flight) instead of 256 serial uniform loads; zsq rebuilt
// numpy-exactly from registers via shuffles; cross z via __shfl broadcast.
__global__ __launch_bounds__(256) void rescue_kernel(const float* __restrict__ z,
                                                     int* __restrict__ out) {
    const int lane = threadIdx.x & 63;
    const int wg   = (int)blockIdx.x * 4 + (int)(threadIdx.x >> 6);
    const int nw   = (int)gridDim.x * 4;
    const int count = g_count;

    for (int it = wg; it < count; it += nw) {
        const int n = g_list[it];
        const float* zp = z + ((size_t)(n >> 10) << 18) + (n & 1023);

        float zf[4], xsq[4];
        #pragma unroll
        for (int q = 0; q < 4; ++q) zf[q] = zp[(size_t)((q << 6) + lane) << 10];
        #pragma unroll
        for (int q = 0; q < 4; ++q) xsq[q] = zf[q] * zf[q];  // separately rounded

        // numpy pairwise zsq. Chain for j=lane&7: r = a[j]^2; r += a[8t+j]^2,
        // t ascending (t<8 -> reg even, t>=8 -> reg odd). Fold = xor butterflies
        // (commutative adds reproduce ((r0+r1)+(r2+r3))+((r4+r5)+(r6+r7)) bitwise).
        const int j = lane & 7;
        float r0 = __shfl(xsq[0], j);
        #pragma unroll
        for (int t = 1; t < 8; ++t) r0 += __shfl(xsq[0], 8*t + j);
        #pragma unroll
        for (int t = 0; t < 8; ++t) r0 += __shfl(xsq[1], 8*t + j);
        float r1 = __shfl(xsq[2], j);
        #pragma unroll
        for (int t = 1; t < 8; ++t) r1 += __shfl(xsq[2], 8*t + j);
        #pragma unroll
        for (int t = 0; t < 8; ++t) r1 += __shfl(xsq[3], 8*t + j);
        r0 = r0 + __shfl_xor(r0, 1);
        r0 = r0 + __shfl_xor(r0, 2);
        r0 = r0 + __shfl_xor(r0, 4);
        r1 = r1 + __shfl_xor(r1, 1);
        r1 = r1 + __shfl_xor(r1, 2);
        r1 = r1 + __shfl_xor(r1, 4);
        const float zsq = r0 + r1;

        // Exact cross in fp64 (fp32 inputs widened: exact). lane owns k=lane+64j.
        // Two chains per code to halve dependent-FMA latency; fp64 merge exact
        // to ~1e-17 (same risk profile as the validated single chain).
        double a8a[8], a8b[8];
        #pragma unroll
        for (int jj = 0; jj < 8; ++jj) { a8a[jj] = 0.0; a8b[jj] = 0.0; }
        for (int dq = 0; dq < D_DIM / 4; ++dq) {
            const int d0 = dq * 4;
            double zd0 = (double)__shfl(zf[(d0    ) >> 6], (d0    ) & 63);
            double zd1 = (double)__shfl(zf[(d0 + 1) >> 6], (d0 + 1) & 63);
            double zd2 = (double)__shfl(zf[(d0 + 2) >> 6], (d0 + 2) & 63);
            double zd3 = (double)__shfl(zf[(d0 + 3) >> 6], (d0 + 3) & 63);
            #pragma unroll
            for (int jj = 0; jj < 8; ++jj) {
                float4 c4 = g_cbF4[dq * K_CODES + lane + (jj << 6)];  // coalesced
                a8a[jj] = fma((double)c4.x, zd0, a8a[jj]);
                a8a[jj] = fma((double)c4.y, zd1, a8a[jj]);
                a8b[jj] = fma((double)c4.z, zd2, a8b[jj]);
                a8b[jj] = fma((double)c4.w, zd3, a8b[jj]);
            }
        }

        // numpy final ops: t = fl32(zsq - 2*c32); dist = fl32(t + esq). First-idx ties.
        float best = __builtin_inff(); int bi = 0x7FFFFFFF;
        #pragma unroll
        for (int jj = 0; jj < 8; ++jj) {
            int kk = lane + (jj << 6);
            float c32 = (float)(a8a[jj] + a8b[jj]);
            float t = zsq - 2.0f * c32;
            float dist = t + g_esq[kk];
            if (dist < best || (dist == best && kk < bi)) { best = dist; bi = kk; }
        }
        #pragma unroll
        for (int off = 32; off; off >>= 1) {
            float ob = __shfl_xor(best, off);
            int   oi = __shfl_xor(bi, off);
            if (ob < best || (ob == best && oi < bi)) { best = ob; bi = oi; }
        }
        if (lane == 0) out[n] = bi;
    }
}

extern "C" void kernel_launch(void* const* d_in, const int* in_sizes, int n_in,
                              void* d_out, int out_size, void* d_ws, size_t ws_size,
                              hipStream_t stream) {
    const float* z_e_x    = (const float*)d_in[0];   // [64, 256, 32, 32] fp32
    const float* codebook = (const float*)d_in[1];   // [512, 256] fp32
    int* out = (int*)d_out;                          // [65536] int32

    prep_kernel<<<dim3(2), dim3(256), 0, stream>>>(codebook);
    pass1_kernel<<<dim3(2048), dim3(512), 0, stream>>>(z_e_x, out);
    rescue_kernel<<<dim3(512), dim3(256), 0, stream>>>(z_e_x, out);
}

// Round 6
// 416.217 us; speedup vs baseline: 1.7046x; 1.0217x over previous
//
#include <hip/hip_runtime.h>

// contract(off): numpy-emulating fp32 ops (esq, rescue zsq/dist) must round mul
// and add separately. Explicit fmaf/fma and MFMA are unaffected.
#pragma clang fp contract(off)

#define K_CODES 512
#define D_DIM 256
#define NPIX 65536
#define TAU 3e-4f
// z layout [B=64, D=256, H*W=1024]; pixel n = b*1024 + hw.

typedef __attribute__((ext_vector_type(8))) short bf16x8;
typedef __attribute__((ext_vector_type(4))) float f32x4;

__device__ unsigned short g_zhi[NPIX * D_DIM];   // zT hi, [pixel][d] bf16 bits
__device__ unsigned short g_zlo[NPIX * D_DIM];   // zT lo
__device__ unsigned short g_chi[K_CODES * D_DIM]; // cb hi, [code][d]
__device__ unsigned short g_clo[K_CODES * D_DIM]; // cb lo
__device__ float4 g_cbF4[(D_DIM / 4) * K_CODES]; // fp32 cb for rescue (exact)
__device__ float  g_esq[K_CODES];                // numpy-pairwise fp32 ||e_k||^2
__device__ int    g_list[NPIX];
__device__ int    g_count;

static __device__ __forceinline__ unsigned short f2bf(float x) {
    unsigned u = __float_as_uint(x);
    return (unsigned short)((u + 0x7FFFu + ((u >> 16) & 1u)) >> 16);   // RNE
}
static __device__ __forceinline__ float bf2f(unsigned short h) {
    return __uint_as_float((unsigned)h << 16);
}

__global__ __launch_bounds__(256) void prep_cb(const float* __restrict__ cb) {
    if (blockIdx.x == 0 && threadIdx.x == 0) g_count = 0;
    int k = blockIdx.x * 256 + threadIdx.x;
    if (k >= K_CODES) return;
    const float* row = cb + k * D_DIM;
    for (int d = 0; d < D_DIM; ++d) {
        float x = row[d];
        unsigned short h = f2bf(x);
        g_chi[k * D_DIM + d] = h;
        g_clo[k * D_DIM + d] = f2bf(x - bf2f(h));   // x-hi exact (Sterbenz)
    }
    for (int dq = 0; dq < D_DIM / 4; ++dq)
        g_cbF4[dq * K_CODES + k] = make_float4(row[4*dq], row[4*dq+1], row[4*dq+2], row[4*dq+3]);

    // e_sq = np.sum(row*row): pairwise n=256 -> p(0:128)+p(128:256); 8 accums each.
    float s[2];
    for (int blk = 0; blk < 2; ++blk) {
        const float* a = row + blk * 128;
        float r[8];
        #pragma unroll
        for (int j = 0; j < 8; ++j) { float x = a[j]; r[j] = x * x; }
        for (int i = 8; i < 128; i += 8)
            #pragma unroll
            for (int j = 0; j < 8; ++j) { float x = a[i + j]; r[j] += x * x; }
        s[blk] = ((r[0] + r[1]) + (r[2] + r[3])) + ((r[4] + r[5]) + (r[6] + r[7]));
    }
    g_esq[k] = s[0] + s[1];
}

// Transpose z [b][d][hw] fp32 -> zT_hi/zT_lo [pixel][d] bf16. Block = 64 pixels.
__global__ __launch_bounds__(256) void prep_z(const float* __restrict__ z) {
    __shared__ float lds[64 * 68];          // [d_rel][hw_rel], stride 68 (16B-aligned rows)
    const int n0  = blockIdx.x * 64;        // 64 | 1024 -> same b
    const int b   = n0 >> 10;
    const int hw0 = n0 & 1023;
    const int t   = threadIdx.x;

    for (int dc = 0; dc < 4; ++dc) {        // d-chunks of 64
        {   // load 64 d x 64 hw, coalesced along hw
            const int dd = t >> 2, q = t & 3;
            const float* src = z + ((size_t)b << 18) + (size_t)(dc * 64 + dd) * 1024 + hw0;
            #pragma unroll
            for (int i = 0; i < 4; ++i) {
                float4 v = *(const float4*)(src + (q + 4 * i) * 4);
                *(float4*)&lds[dd * 68 + (q + 4 * i) * 4] = v;
            }
        }
        __syncthreads();
        {   // write 16 d's per thread for pixel p, contiguous in zT
            const int p = t >> 2, dq = t & 3;
            unsigned short h[16], l[16];
            #pragma unroll
            for (int i = 0; i < 16; ++i) {
                float x = lds[(dq * 16 + i) * 68 + p];
                h[i] = f2bf(x);
                l[i] = f2bf(x - bf2f(h[i]));
            }
            size_t base = (size_t)(n0 + p) * D_DIM + dc * 64 + dq * 16;
            *(uint4*)&g_zhi[base]     = *(uint4*)&h[0];
            *(uint4*)&g_zhi[base + 8] = *(uint4*)&h[8];
            *(uint4*)&g_zlo[base]     = *(uint4*)&l[0];
            *(uint4*)&g_zlo[base + 8] = *(uint4*)&l[8];
        }
        __syncthreads();
    }
}

// Pass 1 (MFMA): block = 512 thr = 8 waves; 64 pixels x 512 codes; K' = 768
// (seg0 zh*ch, seg1 zh*cl, seg2 zl*ch). Wave w owns codes [w*64, w*64+64):
// 4x4 tiles of 16x16x32 MFMA. Double-buffered LDS, 1 barrier/step.
__global__ __launch_bounds__(512) void pass1_mfma(int* __restrict__ out) {
    __shared__ unsigned short Abuf[2][64 * 40];    // [m][k], stride 40 (pad)
    __shared__ unsigned short Bbuf[2][512 * 40];   // [n][k], stride 40
    __shared__ float s_mn[8][64];
    __shared__ int   s_ixl[8][64];
    __shared__ float s_gm[64];
    __shared__ int   s_gi[64];
    __shared__ int   s_cnt[64];

    const int lane = threadIdx.x & 63;
    const int w    = __builtin_amdgcn_readfirstlane((int)(threadIdx.x >> 6));
    const int l16  = lane & 15, quad = lane >> 4;
    const int n0   = (int)blockIdx.x * 64;

    const int sm  = threadIdx.x >> 3;   // A staging: pixel row
    const int skq = threadIdx.x & 7;    // A staging: k-quad (4 shorts)
    const int sn  = threadIdx.x;        // B staging: code row

    f32x4 acc[4][4];
    #pragma unroll
    for (int i = 0; i < 4; ++i)
        #pragma unroll
        for (int j = 0; j < 4; ++j)
            acc[i][j] = (f32x4){0.f, 0.f, 0.f, 0.f};

    // stage step 0
    {
        const unsigned short* zs = g_zhi; const unsigned short* cs = g_chi;
        *(uint2*)&Abuf[0][sm * 40 + skq * 4] =
            *(const uint2*)&zs[(size_t)(n0 + sm) * D_DIM + skq * 4];
        #pragma unroll
        for (int j = 0; j < 4; ++j)
            *(uint4*)&Bbuf[0][sn * 40 + j * 8] =
                *(const uint4*)&cs[(size_t)sn * D_DIM + j * 8];
    }
    __syncthreads();

    for (int st = 0; st < 24; ++st) {
        const int cur = st & 1, nxt = cur ^ 1;
        uint2 za; uint4 cb4[4];
        if (st < 23) {   // prefetch next step's tiles into registers
            const int sp  = st + 1;
            const int seg = sp >> 3;
            const int k0  = (sp & 7) << 5;
            const unsigned short* zs = (seg == 2) ? g_zlo : g_zhi;
            const unsigned short* cs = (seg == 1) ? g_clo : g_chi;
            za = *(const uint2*)&zs[(size_t)(n0 + sm) * D_DIM + k0 + skq * 4];
            #pragma unroll
            for (int j = 0; j < 4; ++j)
                cb4[j] = *(const uint4*)&cs[(size_t)sn * D_DIM + k0 + j * 8];
        }
        bf16x8 af[4], bfr[4];
        #pragma unroll
        for (int t = 0; t < 4; ++t) {
            af[t]  = *(const bf16x8*)&Abuf[cur][(t * 16 + l16) * 40 + quad * 8];
            bfr[t] = *(const bf16x8*)&Bbuf[cur][(w * 64 + t * 16 + l16) * 40 + quad * 8];
        }
        #pragma unroll
        for (int ti = 0; ti < 4; ++ti)
            #pragma unroll
            for (int tj = 0; tj < 4; ++tj)
                acc[ti][tj] = __builtin_amdgcn_mfma_f32_16x16x32_bf16(
                    af[ti], bfr[tj], acc[ti][tj], 0, 0, 0);
        if (st < 23) {
            *(uint2*)&Abuf[nxt][sm * 40 + skq * 4] = za;
            #pragma unroll
            for (int j = 0; j < 4; ++j)
                *(uint4*)&Bbuf[nxt][sn * 40 + j * 8] = cb4[j];
        }
        __syncthreads();
    }

    // Epilogue. C/D layout (m89/m91-verified): col = lane&15 -> n_loc,
    // row = quad*4 + reg -> m_loc. s[n] = esq[n] - 2*cross (pass-1 space).
    float esqv[4];
    #pragma unroll
    for (int tj = 0; tj < 4; ++tj) esqv[tj] = g_esq[w * 64 + tj * 16 + l16];
    #pragma unroll
    for (int ti = 0; ti < 4; ++ti)
        #pragma unroll
        for (int tj = 0; tj < 4; ++tj)
            #pragma unroll
            for (int r = 0; r < 4; ++r)
                acc[ti][tj][r] = fmaf(-2.0f, acc[ti][tj][r], esqv[tj]);

    // per-row lex argmin within wave (reduce tj, then xor-butterfly over low 4 bits)
    #pragma unroll
    for (int ti = 0; ti < 4; ++ti) {
        #pragma unroll
        for (int r = 0; r < 4; ++r) {
            float bv = __builtin_inff(); int bn = 0x7FFFFFFF;
            #pragma unroll
            for (int tj = 0; tj < 4; ++tj) {
                float s = acc[ti][tj][r];
                int nn = w * 64 + tj * 16 + l16;
                if (s < bv || (s == bv && nn < bn)) { bv = s; bn = nn; }
            }
            #pragma unroll
            for (int off = 1; off <= 8; off <<= 1) {
                float ov = __shfl_xor(bv, off); int on = __shfl_xor(bn, off);
                if (ov < bv || (ov == bv && on < bn)) { bv = ov; bn = on; }
            }
            if (l16 == 0) {
                int m = ti * 16 + quad * 4 + r;
                s_mn[w][m] = bv; s_ixl[w][m] = bn;
            }
        }
    }
    __syncthreads();

    if (threadIdx.x < 64) {
        int m = threadIdx.x;
        float gm = s_mn[0][m]; int gi = s_ixl[0][m];
        #pragma unroll
        for (int q = 1; q < 8; ++q) {
            float v = s_mn[q][m]; int ii = s_ixl[q][m];
            if (v < gm || (v == gm && ii < gi)) { gm = v; gi = ii; }
        }
        s_gm[m] = gm; s_gi[m] = gi; s_cnt[m] = 0;
    }
    __syncthreads();

    // count codes within TAU of the global min (winner included); flag iff >=2
    #pragma unroll
    for (int ti = 0; ti < 4; ++ti) {
        #pragma unroll
        for (int r = 0; r < 4; ++r) {
            int m = ti * 16 + quad * 4 + r;
            float thr = s_gm[m] + TAU;
            int c = 0;
            #pragma unroll
            for (int tj = 0; tj < 4; ++tj) c += (acc[ti][tj][r] < thr) ? 1 : 0;
            #pragma unroll
            for (int off = 1; off <= 8; off <<= 1) c += __shfl_xor(c, off);
            if (l16 == 0) atomicAdd(&s_cnt[m], c);
        }
    }
    __syncthreads();

    if (threadIdx.x < 64) {
        int m = threadIdx.x;
        out[n0 + m] = s_gi[m];
        if (s_cnt[m] >= 2) {
            int pos = atomicAdd(&g_count, 1);
            g_list[pos] = n0 + m;
        }
    }
}

// Rescue: numpy-bit-exact (validated r4/r5). One wave per flagged pixel.
__global__ __launch_bounds__(256) void rescue_kernel(const float* __restrict__ z,
                                                     int* __restrict__ out) {
    const int lane = threadIdx.x & 63;
    const int wg   = (int)blockIdx.x * 4 + (int)(threadIdx.x >> 6);
    const int nw   = (int)gridDim.x * 4;
    const int count = g_count;

    for (int it = wg; it < count; it += nw) {
        const int n = g_list[it];
        const float* zp = z + ((size_t)(n >> 10) << 18) + (n & 1023);

        float zf[4], xsq[4];
        #pragma unroll
        for (int q = 0; q < 4; ++q) zf[q] = zp[(size_t)((q << 6) + lane) << 10];
        #pragma unroll
        for (int q = 0; q < 4; ++q) xsq[q] = zf[q] * zf[q];

        // numpy pairwise zsq via shuffles (bit-exact, validated r5)
        const int j = lane & 7;
        float r0 = __shfl(xsq[0], j);
        #pragma unroll
        for (int t = 1; t < 8; ++t) r0 += __shfl(xsq[0], 8 * t + j);
        #pragma unroll
        for (int t = 0; t < 8; ++t) r0 += __shfl(xsq[1], 8 * t + j);
        float r1 = __shfl(xsq[2], j);
        #pragma unroll
        for (int t = 1; t < 8; ++t) r1 += __shfl(xsq[2], 8 * t + j);
        #pragma unroll
        for (int t = 0; t < 8; ++t) r1 += __shfl(xsq[3], 8 * t + j);
        r0 = r0 + __shfl_xor(r0, 1); r0 = r0 + __shfl_xor(r0, 2); r0 = r0 + __shfl_xor(r0, 4);
        r1 = r1 + __shfl_xor(r1, 1); r1 = r1 + __shfl_xor(r1, 2); r1 = r1 + __shfl_xor(r1, 4);
        const float zsq = r0 + r1;

        double a8a[8], a8b[8];
        #pragma unroll
        for (int jj = 0; jj < 8; ++jj) { a8a[jj] = 0.0; a8b[jj] = 0.0; }
        for (int dq = 0; dq < D_DIM / 4; ++dq) {
            const int d0 = dq * 4;
            double zd0 = (double)__shfl(zf[(d0    ) >> 6], (d0    ) & 63);
            double zd1 = (double)__shfl(zf[(d0 + 1) >> 6], (d0 + 1) & 63);
            double zd2 = (double)__shfl(zf[(d0 + 2) >> 6], (d0 + 2) & 63);
            double zd3 = (double)__shfl(zf[(d0 + 3) >> 6], (d0 + 3) & 63);
            #pragma unroll
            for (int jj = 0; jj < 8; ++jj) {
                float4 c4 = g_cbF4[dq * K_CODES + lane + (jj << 6)];
                a8a[jj] = fma((double)c4.x, zd0, a8a[jj]);
                a8a[jj] = fma((double)c4.y, zd1, a8a[jj]);
                a8b[jj] = fma((double)c4.z, zd2, a8b[jj]);
                a8b[jj] = fma((double)c4.w, zd3, a8b[jj]);
            }
        }

        float best = __builtin_inff(); int bi = 0x7FFFFFFF;
        #pragma unroll
        for (int jj = 0; jj < 8; ++jj) {
            int kk = lane + (jj << 6);
            float c32 = (float)(a8a[jj] + a8b[jj]);
            float t = zsq - 2.0f * c32;
            float dist = t + g_esq[kk];
            if (dist < best || (dist == best && kk < bi)) { best = dist; bi = kk; }
        }
        #pragma unroll
        for (int off = 32; off; off >>= 1) {
            float ob = __shfl_xor(best, off);
            int   oi = __shfl_xor(bi, off);
            if (ob < best || (ob == best && oi < bi)) { best = ob; bi = oi; }
        }
        if (lane == 0) out[n] = bi;
    }
}

extern "C" void kernel_launch(void* const* d_in, const int* in_sizes, int n_in,
                              void* d_out, int out_size, void* d_ws, size_t ws_size,
                              hipStream_t stream) {
    const float* z_e_x    = (const float*)d_in[0];   // [64, 256, 32, 32] fp32
    const float* codebook = (const float*)d_in[1];   // [512, 256] fp32
    int* out = (int*)d_out;                          // [65536] int32

    prep_cb<<<dim3(2), dim3(256), 0, stream>>>(codebook);
    prep_z<<<dim3(1024), dim3(256), 0, stream>>>(z_e_x);
    pass1_mfma<<<dim3(1024), dim3(512), 0, stream>>>(out);
    rescue_kernel<<<dim3(512), dim3(256), 0, stream>>>(z_e_x, out);
}